// Round 2
// 95.759 us; speedup vs baseline: 1.0683x; 1.0683x over previous
//
#include <hip/hip_runtime.h>
#include <hip/hip_bf16.h>
#include <math.h>

#define BATCH 8
#define SEQ   2048
#define DIM   64
#define NEGC  (-1e9f)

typedef short short8  __attribute__((ext_vector_type(8)));
typedef float f32x4   __attribute__((ext_vector_type(4)));
typedef float f32x16  __attribute__((ext_vector_type(16)));

#define MFMA32(a, b, c) __builtin_amdgcn_mfma_f32_32x32x16_bf16((a), (b), (c), 0, 0, 0)

__device__ __forceinline__ ushort f2bf(float x) {   // fp32 -> bf16 bits, RNE
    uint u = __float_as_uint(x);
    uint r = (u + 0x7fffu + ((u >> 16) & 1u)) >> 16;
    return (ushort)r;
}
__device__ __forceinline__ float bf2f(ushort h) {
    return __uint_as_float(((uint)h) << 16);
}

// ---------------------------------------------------------------------------
// ws layout (only first 4MB used):
//   KV frag images, per (b,tile) 16384 B = [Kh 8KB][Vf 8KB]
//     Kh row r (8 bf16, 16B): r=(mt*4+kc)*64+L ->
//        K[key=mt*32+(L&31)][d=kc*16+(L>>5)*8+j]     (A-frag for 32x32x16)
//     Vf row r: r=(dt*4+kc)*64+L ->
//        V[key=kc*16+(L>>5)*8+j][d=dt*32+(L&31)]     (A-frag, V pre-masked)
// ---------------------------------------------------------------------------
__global__ __launch_bounds__(256)
void prep_kv(const float* __restrict__ K, const float* __restrict__ V,
             const float* __restrict__ MV, ushort* __restrict__ ws) {
    __shared__ float raw[64 * 68];
    const int t    = threadIdx.x;
    const int b    = blockIdx.x >> 5;
    const int tile = blockIdx.x & 31;
    const float* Kb  = K  + ((size_t)b * SEQ + tile * 64) * DIM;
    const float* Vb  = V  + ((size_t)b * SEQ + tile * 64) * DIM;
    const float* MVb = MV + (size_t)b * SEQ + tile * 64;
    ushort* wsI = ws + (size_t)(b * 32 + tile) * 8192;

    // ---- K ----
#pragma unroll
    for (int u = 0; u < 4; u++) {
        int f = t + 256 * u, key = f >> 4, d4 = (f & 15) * 4;
        *(float4*)&raw[key * 68 + d4] = *(const float4*)(Kb + (size_t)f * 4);
    }
    __syncthreads();
#pragma unroll
    for (int u = 0; u < 2; u++) {
        int r = t + 256 * u;
        int mt = r >> 8, kc = (r >> 6) & 3, L = r & 63;
        int key = mt * 32 + (L & 31), d0 = kc * 16 + (L >> 5) * 8;
        float4 x0 = *(float4*)&raw[key * 68 + d0];
        float4 x1 = *(float4*)&raw[key * 68 + d0 + 4];
        float xs[8] = {x0.x, x0.y, x0.z, x0.w, x1.x, x1.y, x1.z, x1.w};
        short8 hv;
#pragma unroll
        for (int j = 0; j < 8; j++) hv[j] = (short)f2bf(xs[j]);
        *(short8*)(wsI + r * 8) = hv;
    }
    __syncthreads();

    // ---- V (mask_v folded) ----
#pragma unroll
    for (int u = 0; u < 4; u++) {
        int f = t + 256 * u, key = f >> 4, d4 = (f & 15) * 4;
        float4 x = *(const float4*)(Vb + (size_t)f * 4);
        float mv = MVb[key];
        x.x *= mv; x.y *= mv; x.z *= mv; x.w *= mv;
        *(float4*)&raw[key * 68 + d4] = x;
    }
    __syncthreads();
#pragma unroll
    for (int u = 0; u < 2; u++) {
        int r = t + 256 * u;
        int dt = r >> 8, kc = (r >> 6) & 3, L = r & 63;
        int d = dt * 32 + (L & 31), k0 = kc * 16 + (L >> 5) * 8;
        short8 ov;
#pragma unroll
        for (int j = 0; j < 8; j++) ov[j] = (short)f2bf(raw[(k0 + j) * 68 + d]);
        *(short8*)(wsI + 4096 + r * 8) = ov;
    }
}

// ---------------------------------------------------------------------------
// Fused main: 256 blocks (1/CU) x 512 thr = 8 waves (2 qg x 4 ks).
// Each wave: 32 q x 512 keys (16 chunks of 32 keys), frags loaded DIRECTLY
// from L2-resident ws images into registers (no LDS staging, no barriers in
// the main loop). 2-chunk register pipeline hides L2 latency. 4-way split-K
// merged in LDS at the end; O stored coalesced via LDS transpose.
// b = blockIdx.x & 7 -> one batch per XCD (KV working set 512KB, L2-fit).
// 32x32 C/D: col=lane&31, row=(reg&3)+8*(reg>>2)+4*(lane>>5).
// ---------------------------------------------------------------------------
__global__ __launch_bounds__(512, 2)
void attn_fused(const float* __restrict__ Q, const float* __restrict__ MQ,
                const float* __restrict__ MK, const ushort* __restrict__ ws,
                float* __restrict__ O) {
    __shared__ __align__(16) float Msc[2][3][64][36];
    __shared__ __align__(16) float Oout[2][32][72];

    const int t    = threadIdx.x;
    const int w    = t >> 6;
    const int lane = t & 63;
    const int h    = lane >> 5;
    const int lm   = lane & 31;
    const int qg   = w & 1;        // query group (2 x 32q)
    const int ks   = w >> 1;       // k-split 0..3 (512 keys each)

    const int b  = blockIdx.x & 7;   // XCD-affine batch mapping
    const int qt = blockIdx.x >> 3;
    const int q  = qt * 64 + qg * 32 + lm;

    const float*  MKb = MK + (size_t)b * SEQ;
    const ushort* wsB = ws + (size_t)b * 32 * 8192;

    // ---- Q fragments (B-operand), hi/lo, pre-scaled by 1/8 ----
    short8 qh[4], ql[4];
    {
        const float* Qr = Q + ((size_t)b * SEQ + q) * DIM;
#pragma unroll
        for (int kc = 0; kc < 4; kc++) {
            const float* p = Qr + kc * 16 + h * 8;
            float4 x0 = *(const float4*)p;
            float4 x1 = *(const float4*)(p + 4);
            float xs[8] = {x0.x, x0.y, x0.z, x0.w, x1.x, x1.y, x1.z, x1.w};
#pragma unroll
            for (int j = 0; j < 8; j++) {
                float v   = xs[j] * 0.125f;
                ushort hi = f2bf(v);
                ql[kc][j] = (short)f2bf(v - bf2f(hi));
                qh[kc][j] = (short)hi;
            }
        }
    }
    const float mq   = MQ[(size_t)b * SEQ + q];
    const float apen = NEGC * mq;

    float m = -1e30f, l = 0.0f;
    f32x16 ot0, ot1;
#pragma unroll
    for (int i = 0; i < 16; i++) { ot0[i] = 0.0f; ot1[i] = 0.0f; }

    // ---- register fragment loader: chunk ch = 32 keys ----
    // bias[v][c] = NEGC - apen*mk  precomputed here (off the critical path).
    auto loadch = [&](short8 (&kf)[4], short8 (&vf)[4], f32x4 (&bias)[4], int ch) {
        const int tt = ch >> 1, mt = ch & 1;
        const ushort* img = wsB + (size_t)tt * 8192;
#pragma unroll
        for (int kc = 0; kc < 4; kc++)
            kf[kc] = *(const short8*)(img + (((mt * 4 + kc) << 6) + lane) * 8);
#pragma unroll
        for (int u = 0; u < 4; u++) {
            const int dt = u >> 1, c = u & 1;
            vf[u] = *(const short8*)(img + 4096 + (((dt * 4 + mt * 2 + c) << 6) + lane) * 8);
        }
        const float* mkp = MKb + ch * 32 + h * 4;
#pragma unroll
        for (int v = 0; v < 4; v++) {
            f32x4 mk = *(const f32x4*)(mkp + v * 8);
#pragma unroll
            for (int c = 0; c < 4; c++) bias[v][c] = NEGC - apen * mk[c];
        }
    };

    // ---- one 32-key chunk: QK^T -> online softmax -> PV ----
    auto step = [&](const short8 (&kf)[4], const short8 (&vf)[4],
                    const f32x4 (&bias)[4]) {
        f32x16 st;
#pragma unroll
        for (int i = 0; i < 16; i++) st[i] = 0.0f;
        __builtin_amdgcn_s_setprio(1);
#pragma unroll
        for (int kc = 0; kc < 4; kc++) {
            st = MFMA32(kf[kc], qh[kc], st);
            st = MFMA32(kf[kc], ql[kc], st);
        }
        __builtin_amdgcn_s_setprio(0);

        float sv[16];
#pragma unroll
        for (int v = 0; v < 4; v++)
#pragma unroll
            for (int c = 0; c < 4; c++)
                sv[v * 4 + c] = st[v * 4 + c] + bias[v][c];
        float cm = sv[0];
#pragma unroll
        for (int i = 1; i < 16; i++) cm = fmaxf(cm, sv[i]);
        cm = fmaxf(cm, __shfl_xor(cm, 32));
        if (!__all(cm <= m)) {            // exact skip: no lane's max grew
            float nm    = fmaxf(m, cm);
            float alpha = __expf(m - nm);
            m = nm;
            l *= alpha;
            ot0 *= alpha; ot1 *= alpha;
        }
        float p[16], cs = 0.0f;
#pragma unroll
        for (int i = 0; i < 16; i++) { p[i] = __expf(sv[i] - m); cs += p[i]; }
        cs += __shfl_xor(cs, 32);
        l += cs;

        // ---- P: C-layout -> B-frags via half-wave exchange ----
        uint g[4][2], x[4][2];
#pragma unroll
        for (int v = 0; v < 4; v++) {
            __hip_bfloat162 c0 = __float22bfloat162_rn(make_float2(p[v*4+0], p[v*4+1]));
            __hip_bfloat162 c1 = __float22bfloat162_rn(make_float2(p[v*4+2], p[v*4+3]));
            __builtin_memcpy(&g[v][0], &c0, 4);
            __builtin_memcpy(&g[v][1], &c1, 4);
            x[v][0] = (uint)__shfl_xor((int)g[v][0], 32);
            x[v][1] = (uint)__shfl_xor((int)g[v][1], 32);
        }
        uint pbw[2][4];
        pbw[0][0] = h ? x[1][0] : g[0][0];
        pbw[0][1] = h ? x[1][1] : g[0][1];
        pbw[0][2] = h ? g[1][0] : x[0][0];
        pbw[0][3] = h ? g[1][1] : x[0][1];
        pbw[1][0] = h ? x[3][0] : g[2][0];
        pbw[1][1] = h ? x[3][1] : g[2][1];
        pbw[1][2] = h ? g[3][0] : x[2][0];
        pbw[1][3] = h ? g[3][1] : x[2][1];

        __builtin_amdgcn_s_setprio(1);
#pragma unroll
        for (int c = 0; c < 2; c++) {
            short8 pb;
            __builtin_memcpy(&pb, &pbw[c][0], 16);
            ot0 = MFMA32(vf[c],     pb, ot0);
            ot1 = MFMA32(vf[2 + c], pb, ot1);
        }
        __builtin_amdgcn_s_setprio(0);
    };

    // ---- main loop: 16 chunks, 2-deep register pipeline, NO barriers ----
    short8 kA[4], vA[4], kB[4], vB[4];
    f32x4  bA[4], bB[4];
    const int ch0 = ks * 16;
    loadch(kA, vA, bA, ch0);
#pragma unroll 1
    for (int i = 0; i < 8; i++) {
        loadch(kB, vB, bB, ch0 + 2 * i + 1);
        step(kA, vA, bA);
        if (i < 7) loadch(kA, vA, bA, ch0 + 2 * i + 2);
        step(kB, vB, bB);
    }

    // ---- 4-way split-K merge in LDS ----
    if (ks != 0) {
        float* sc = &Msc[qg][ks - 1][lane][0];
#pragma unroll
        for (int i = 0; i < 4; i++) {
            f32x4 r0, r1;
#pragma unroll
            for (int c = 0; c < 4; c++) { r0[c] = ot0[i*4+c]; r1[c] = ot1[i*4+c]; }
            *(f32x4*)&sc[i * 4]      = r0;
            *(f32x4*)&sc[16 + i * 4] = r1;
        }
        sc[32] = m;
        sc[33] = l;
    }
    __syncthreads();
    if (ks == 0) {
#pragma unroll
        for (int pp = 0; pp < 3; pp++) {
            const float* sc = &Msc[qg][pp][lane][0];
            float mb = sc[32], lb = sc[33];
            float nm = fmaxf(m, mb);
            float fa = __expf(m - nm), fb = __expf(mb - nm);
            m = nm;
            l = l * fa + lb * fb;
#pragma unroll
            for (int i = 0; i < 16; i++) {
                ot0[i] = ot0[i] * fa + sc[i] * fb;
                ot1[i] = ot1[i] * fa + sc[16 + i] * fb;
            }
        }
        const float inv = 1.0f / l;
        // write normalized O^T fragments into LDS tile [q][d]
#pragma unroll
        for (int dt = 0; dt < 2; dt++)
#pragma unroll
            for (int rq = 0; rq < 4; rq++) {
                f32x4 r;
#pragma unroll
                for (int c = 0; c < 4; c++)
                    r[c] = (dt ? ot1[rq * 4 + c] : ot0[rq * 4 + c]) * inv;
                *(f32x4*)&Oout[qg][lm][dt * 32 + rq * 8 + h * 4] = r;
            }
    }
    __syncthreads();

    // ---- cooperative coalesced store: 64 q x 64 d ----
    float* Ob = O + ((size_t)b * SEQ + qt * 64) * DIM;
#pragma unroll
    for (int u = 0; u < 2; u++) {
        int f = t + 512 * u;                 // 0..1023
        int row = f >> 4, d4 = (f & 15) * 4;
        f32x4 val = *(const f32x4*)&Oout[row >> 5][row & 31][d4];
        *(f32x4*)(Ob + (size_t)row * DIM + d4) = val;
    }
}

extern "C" void kernel_launch(void* const* d_in, const int* in_sizes, int n_in,
                              void* d_out, int out_size, void* d_ws, size_t ws_size,
                              hipStream_t stream) {
    const float* Q  = (const float*)d_in[0];
    const float* K  = (const float*)d_in[1];
    const float* V  = (const float*)d_in[2];
    const float* MQ = (const float*)d_in[3];
    const float* MK = (const float*)d_in[4];
    const float* MV = (const float*)d_in[5];
    float* O = (float*)d_out;

    ushort* wsKV = (ushort*)d_ws;

    prep_kv   <<<dim3(256), dim3(256), 0, stream>>>(K, V, MV, wsKV);
    attn_fused<<<dim3(256), dim3(512), 0, stream>>>(Q, MQ, MK, wsKV, O);
}